// Round 1
// baseline (2348.278 us; speedup 1.0000x reference)
//
#include <hip/hip_runtime.h>
#include <cmath>
#include <cstdint>

// HashPINN fused forward: 16-level hash-grid encode + 4-layer MLP, fp32.
// One thread per point. Weights read via wave-uniform global loads (s_load).

#define HASH_SZ (1u << 19)
#define HMASK   (HASH_SZ - 1u)

struct ResArr { int r[16]; };

__global__ __launch_bounds__(256, 2)
void hashpinn_fused(const float* __restrict__ x,
                    const float* __restrict__ table,
                    const float* __restrict__ W1, const float* __restrict__ b1,
                    const float* __restrict__ W2, const float* __restrict__ b2,
                    const float* __restrict__ W3, const float* __restrict__ b3,
                    const float* __restrict__ Wo, const float* __restrict__ bo,
                    float* __restrict__ out, int n, ResArr rv)
{
    const int p = blockIdx.x * 256 + threadIdx.x;
    if (p >= n) return;

    const float px = x[3*p + 0];
    const float py = x[3*p + 1];
    const float pz = x[3*p + 2];

    float feat[32];

    #pragma unroll
    for (int l = 0; l < 16; ++l) {
        const int res = rv.r[l];
        const float rf = (float)(res - 1);
        const float fx = px * rf, fy = py * rf, fz = pz * rf;
        int ix = (int)floorf(fx), iy = (int)floorf(fy), iz = (int)floorf(fz);
        ix = min(max(ix, 0), res - 2);
        iy = min(max(iy, 0), res - 2);
        iz = min(max(iz, 0), res - 2);
        // frac from the CLIPPED integer position (matches reference)
        const float tx = fx - (float)ix, ty = fy - (float)iy, tz = fz - (float)iz;
        const float sx = 1.f - tx, sy = 1.f - ty, sz = 1.f - tz;

        const float2* tbl = (const float2*)table + (size_t)l * HASH_SZ;
        const bool dense = ((long long)res * res * res <= (long long)HASH_SZ);

        float a0 = 0.f, a1 = 0.f;
        #pragma unroll
        for (int c = 0; c < 8; ++c) {
            const int ox = (c >> 2) & 1, oy = (c >> 1) & 1, oz = c & 1;
            const uint32_t cx = (uint32_t)(ix + ox);
            const uint32_t cy = (uint32_t)(iy + oy);
            const uint32_t cz = (uint32_t)(iz + oz);
            uint32_t idx;
            if (dense) {
                idx = cx + (uint32_t)res * (cy + (uint32_t)res * cz);
            } else {
                idx = (cx * 1u ^ cy * 2654435761u ^ cz * 805459861u) & HMASK;
            }
            const float2 v = tbl[idx];
            const float w = (ox ? tx : sx) * (oy ? ty : sy) * (oz ? tz : sz);
            a0 = fmaf(w, v.x, a0);
            a1 = fmaf(w, v.y, a1);
        }
        feat[2*l + 0] = a0;
        feat[2*l + 1] = a1;
    }

    // ---- MLP: 32 -> 64 -> 64 -> 64 -> 1, fp32 vector ALU ----
    float A[64], B[64];

    #pragma unroll
    for (int j = 0; j < 64; ++j) A[j] = b1[j];
    #pragma unroll
    for (int k = 0; k < 32; ++k) {
        const float h = feat[k];
        #pragma unroll
        for (int j = 0; j < 64; ++j) A[j] = fmaf(h, W1[k*64 + j], A[j]);
    }

    // layers 2 and 3 share code (halves I-footprint); pointers are uniform
    #pragma unroll 1
    for (int it = 0; it < 2; ++it) {
        const float* __restrict__ W  = it ? W3 : W2;
        const float* __restrict__ bb = it ? b3 : b2;
        #pragma unroll
        for (int j = 0; j < 64; ++j) { A[j] = fmaxf(A[j], 0.f); B[j] = bb[j]; }
        #pragma unroll
        for (int k = 0; k < 64; ++k) {
            const float h = A[k];
            #pragma unroll
            for (int j = 0; j < 64; ++j) B[j] = fmaf(h, W[k*64 + j], B[j]);
        }
        #pragma unroll
        for (int j = 0; j < 64; ++j) A[j] = B[j];
    }

    float o = bo[0];
    #pragma unroll
    for (int j = 0; j < 64; ++j) o = fmaf(fmaxf(A[j], 0.f), Wo[j], o);

    out[p] = o;
}

extern "C" void kernel_launch(void* const* d_in, const int* in_sizes, int n_in,
                              void* d_out, int out_size, void* d_ws, size_t ws_size,
                              hipStream_t stream) {
    const float* x     = (const float*)d_in[0];
    const float* table = (const float*)d_in[1];
    const float* W1    = (const float*)d_in[2];
    const float* b1    = (const float*)d_in[3];
    const float* W2    = (const float*)d_in[4];
    const float* b2    = (const float*)d_in[5];
    const float* W3    = (const float*)d_in[6];
    const float* b3    = (const float*)d_in[7];
    const float* Wo    = (const float*)d_in[8];
    const float* bo    = (const float*)d_in[9];
    float* out = (float*)d_out;

    const int n = in_sizes[0] / 3;

    // Replicate numpy's resolution computation bit-for-bit with host libm:
    // scale = exp2(log2(2048/16)/15); res_l = int(ceil(16 * scale**l))
    ResArr rv;
    const double scale = std::exp2(std::log2(2048.0 / 16.0) / 15.0);
    for (int l = 0; l < 16; ++l)
        rv.r[l] = (int)std::ceil(16.0 * std::pow(scale, (double)l));

    const int blocks = (n + 255) / 256;
    hipLaunchKernelGGL(hashpinn_fused, dim3(blocks), dim3(256), 0, stream,
                       x, table, W1, b1, W2, b2, W3, b3, Wo, bo, out, n, rv);
}